// Round 8
// baseline (146.119 us; speedup 1.0000x reference)
//
#include <hip/hip_runtime.h>
#include <hip/hip_cooperative_groups.h>

namespace cg = cooperative_groups;

// Chamfer loss between subsampled point clouds — SINGLE cooperative dispatch.
// srcA: (64000,2) fp32 -> A = 8000 pts  (fp32 linspace trunc, matches jnp)
// srcB: (80000,2) fp32 -> B = 10000 pts
// out  = 0.5 * ( mean_i min_j |A_i - B_j| + mean_j min_i |A_i - B_j| )
//
// Round-7 accounting: timed window = 41us harness poison-fill (fixed) +
// our dispatches + ~8us per inter-dispatch gap. 3 dispatches made round 7
// SLOWER than round 1 despite better kernels. Fix: fuse into ONE
// hipLaunchCooperativeKernel with grid.sync() between phases.
//
// Phase 1 (all 511 blocks, ~2/CU): block = (2048-row group, 157-col slice).
//   Inline linspace gather (rounds 0/1 proved fine at this amortization).
//   Cols staged in LDS as (2qx, 2qy, -|q|^2): expanded form
//     argmin_j |p-q|^2 == argmax_j (2p.q - |q|^2)
//     M = fmax(M, fma(px,qx, fma(py,qy, -|q|^2)))   3 VALU ops/pair,
//   one ds_read_b128 broadcast feeds 24 VALU (RPT=8) -> VALU-bound ~8us.
//   Partial min-d^2 = pp - M stored plain+coalesced (NO atomics: round 6
//   showed per-row device atomicMin = far-memory RMW storm, 81us).
// grid.sync()
// Phase 2 (blocks 0..281): round-4 reduce structure (measured fast):
//   64 rows x 4 chunk-slices per block, coalesced strided loads at full
//   occupancy, LDS cross-slice min, clamp-at-0, sqrt, wave-reduce,
//   one atomicAdd per block. *out zeroed by block 0 pre-sync.

#define SRC_A 64000
#define SRC_B 80000
#define NA 8000
#define NB 10000

#define BLOCK 256
#define RPT 8
#define RPB (BLOCK * RPT)      // 2048 rows per block
#define SLICE 157              // cols per block (staged once in LDS)

#define G1 4                   // ceil(NA/RPB)   row-groups, pass 1 (A rows)
#define S1 64                  // ceil(NB/SLICE) col-slices, pass 1 (B cols)
#define G2 5                   // ceil(NB/RPB)   row-groups, pass 2 (B rows)
#define S2 51                  // ceil(NA/SLICE) col-slices, pass 2 (A cols)
#define NBLK1 (G1 * S1)        // 256
#define NBLK2 (G2 * S2)        // 255  -> 511 blocks total

#define PSTR1 (G1 * RPB)       // 8192  (padded rows, pass 1)
#define PSTR2 (G2 * RPB)       // 10240 (padded rows, pass 2)
#define PART2_OFF (S1 * PSTR1) // floats; P1 @ 0, P2 @ PART2_OFF (~4.2 MB total)

#define DELTA_A ((float)(SRC_A - 1) / (float)(NA - 1))
#define DELTA_B ((float)(SRC_B - 1) / (float)(NB - 1))

// phase-2 geometry (round-4 reduce)
#define RB_ROWS 64
#define RB1 125   // 8000/64 (exact)
#define RB2 157   // ceil(10000/64)

__global__ __launch_bounds__(BLOCK) void chamfer_all(
        const float2* __restrict__ srcA, const float2* __restrict__ srcB,
        float* __restrict__ ws, float* __restrict__ out) {
    if (blockIdx.x == 0 && threadIdx.x == 0) *out = 0.0f;  // pre-sync init

    // ---------------- phase 1: chamfer partials ----------------
    const bool p1 = (int)blockIdx.x < NBLK1;
    const float2* rowsS; const float2* colsS; float* P;
    float rowD, colD; int rowMax, colMax, nrows, ncols, g, s, pstr;
    if (p1) {
        int f = (int)blockIdx.x;
        g = f % G1; s = f / G1;
        rowsS = srcA; rowD = DELTA_A; rowMax = SRC_A - 1; nrows = NA;
        colsS = srcB; colD = DELTA_B; colMax = SRC_B - 1; ncols = NB;
        P = ws; pstr = PSTR1;
    } else {
        int f = (int)blockIdx.x - NBLK1;
        g = f % G2; s = f / G2;
        rowsS = srcB; rowD = DELTA_B; rowMax = SRC_B - 1; nrows = NB;
        colsS = srcA; colD = DELTA_A; colMax = SRC_A - 1; ncols = NA;
        P = ws + PART2_OFF; pstr = PSTR2;
    }

    // stage this block's column slice in LDS as (2qx, 2qy, -|q|^2, 0)
    __shared__ __align__(16) float4 sc[SLICE];
    int c0 = s * SLICE;
    int cw = ncols - c0; if (cw > SLICE) cw = SLICE;
    if ((int)threadIdx.x < cw) {
        int cidx = (int)((float)(c0 + (int)threadIdx.x) * colD);
        if (cidx > colMax) cidx = colMax;
        float2 q = colsS[cidx];
        float n2 = fmaf(q.x, q.x, q.y * q.y);
        sc[threadIdx.x] = make_float4(q.x + q.x, q.y + q.y, -n2, 0.0f);
    }
    __syncthreads();

    // rows: inline gather (clamp load, guard store)
    float px[RPT], py[RPT], pp[RPT], M[RPT];
    int r0 = g * RPB + (int)threadIdx.x;
#pragma unroll
    for (int i = 0; i < RPT; ++i) {
        int r = r0 + i * BLOCK;
        int l = r < nrows ? r : nrows - 1;
        int ridx = (int)((float)l * rowD);
        if (ridx > rowMax) ridx = rowMax;
        float2 q = rowsS[ridx];
        px[i] = q.x; py[i] = q.y;
        pp[i] = fmaf(q.x, q.x, q.y * q.y);
        M[i] = -__builtin_inff();
    }

    if (cw == SLICE) {
        // hot path (113 of 115 slices): compile-time trip count
#pragma unroll 4
        for (int k = 0; k < SLICE; ++k) {
            float4 q = sc[k];  // broadcast across the wave: conflict-free
#pragma unroll
            for (int i = 0; i < RPT; ++i)
                M[i] = fmaxf(M[i], fmaf(px[i], q.x, fmaf(py[i], q.y, q.z)));
        }
    } else {
        for (int k = 0; k < cw; ++k) {
            float4 q = sc[k];
#pragma unroll
            for (int i = 0; i < RPT; ++i)
                M[i] = fmaxf(M[i], fmaf(px[i], q.x, fmaf(py[i], q.y, q.z)));
        }
    }

    // plain coalesced stores of partial min d^2 (no atomics)
#pragma unroll
    for (int i = 0; i < RPT; ++i) {
        int r = r0 + i * BLOCK;
        if (r < nrows) P[s * pstr + r] = pp[i] - M[i];
    }

    // ---------------- grid-wide barrier ----------------
    cg::this_grid().sync();

    // ---------------- phase 2: reduce (blocks 0..281) ----------------
    int b = (int)blockIdx.x;
    if (b >= RB1 + RB2) return;

    int t  = (int)threadIdx.x;
    int rl = t & 63;        // row within block
    int sl = t >> 6;        // chunk-slice 0..3
    const float* Q; int nr2, nch, ps2, rbase; float scale;
    if (b < RB1) {
        Q = ws;             nr2 = NA; nch = S1; ps2 = PSTR1;
        rbase = b * RB_ROWS;          scale = 0.5f / (float)NA;
    } else {
        Q = ws + PART2_OFF; nr2 = NB; nch = S2; ps2 = PSTR2;
        rbase = (b - RB1) * RB_ROWS;  scale = 0.5f / (float)NB;
    }
    int r = rbase + rl;                 // < ps2 (padded); value guarded at use
    int per = (nch + 3) >> 2;
    int cb = sl * per;
    int ce = cb + per; if (ce > nch) ce = nch;

    float mn = __builtin_inff();
#pragma unroll 8
    for (int c = cb; c < ce; ++c) mn = fminf(mn, Q[c * ps2 + r]);

    __shared__ float red[4][RB_ROWS];
    red[sl][rl] = mn;
    __syncthreads();

    if (t < 64) {
        float m = fminf(fminf(red[0][rl], red[1][rl]),
                        fminf(red[2][rl], red[3][rl]));
        m = fmaxf(m, 0.0f);  // expanded form can round slightly negative
        float v = (r < nr2) ? sqrtf(m) * scale : 0.0f;
        for (int off = 32; off > 0; off >>= 1) v += __shfl_down(v, off, 64);
        if (rl == 0) atomicAdd(out, v);
    }
}

extern "C" void kernel_launch(void* const* d_in, const int* in_sizes, int n_in,
                              void* d_out, int out_size, void* d_ws, size_t ws_size,
                              hipStream_t stream) {
    (void)in_sizes; (void)n_in; (void)out_size; (void)ws_size;
    const float2* srcA = (const float2*)d_in[0];  // img_render_points (1000*64*2)
    const float2* srcB = (const float2*)d_in[1];  // ref point cloud (80000*2)
    float* ws = (float*)d_ws;
    float* out = (float*)d_out;

    void* args[] = { (void*)&srcA, (void*)&srcB, (void*)&ws, (void*)&out };
    hipLaunchCooperativeKernel((const void*)chamfer_all, dim3(NBLK1 + NBLK2),
                               dim3(BLOCK), args, 0, stream);
}

// Round 9
// 76.674 us; speedup vs baseline: 1.9057x; 1.9057x over previous
//
#include <hip/hip_runtime.h>

// Chamfer loss between subsampled point clouds — 2 dispatches, no exotic sync.
// srcA: (64000,2) fp32 -> A = 8000 pts  (fp32 linspace trunc, matches jnp)
// srcB: (80000,2) fp32 -> B = 10000 pts
// out  = 0.5 * ( mean_i min_j |A_i - B_j| + mean_j min_i |A_i - B_j| )
//
// Session ledger (measured):
//  - per-row device atomicMin storm: 81us (round 6). NEVER per-element atomics.
//  - cooperative grid.sync() over 511 blocks: ~60us of spin/L2-drain across
//    8 non-coherent XCDs (round 8). NEVER grid-wide sync for a 13us workload.
//  - inter-dispatch gap ~8us: 3 dispatches beat by 2 (round 7 vs 1).
//  - inline linspace gather inside chamfer: fine (round 8 phase 1) -> no
//    pack dispatch needed.
//  - LDS float4 broadcast cols + expanded-form 3-op inner loop: chamfer ~9us
//    (rounds 7/8). 282-block slice-parallel reduce: ~4-5us (rounds 4/7).
//
// This version = round 7 minus pack_init: the two proven kernels only.
//
// Expanded form: argmin_j |p-q_j|^2 == argmax_j (2p.q_j - |q_j|^2);
//   M = fmax(M, fma(px,qx, fma(py,qy, -|q|^2)))  = 3 VALU ops/pair.
// |p|^2 re-added at store; clamp-at-0 + sqrt in the reduce (monotone).

#define SRC_A 64000
#define SRC_B 80000
#define NA 8000
#define NB 10000

#define BLOCK 256
#define RPT 8
#define RPB (BLOCK * RPT)      // 2048 rows per block
#define SLICE 157              // cols per block (staged once in LDS)

#define G1 4                   // ceil(NA/RPB)   row-groups, pass 1 (A rows)
#define S1 64                  // ceil(NB/SLICE) col-slices, pass 1 (B cols)
#define G2 5                   // ceil(NB/RPB)   row-groups, pass 2 (B rows)
#define S2 51                  // ceil(NA/SLICE) col-slices, pass 2 (A cols)
#define NBLK1 (G1 * S1)        // 256
#define NBLK2 (G2 * S2)        // 255  -> 511 blocks (~2/CU, balanced)

#define PSTR1 (G1 * RPB)       // 8192  (padded rows, pass 1)
#define PSTR2 (G2 * RPB)       // 10240 (padded rows, pass 2)
#define PART2_OFF (S1 * PSTR1) // floats; P1 @ 0, P2 @ PART2_OFF (~4.2 MB total)

#define DELTA_A ((float)(SRC_A - 1) / (float)(NA - 1))
#define DELTA_B ((float)(SRC_B - 1) / (float)(NB - 1))

__global__ __launch_bounds__(BLOCK) void chamfer_partial(
        const float2* __restrict__ srcA, const float2* __restrict__ srcB,
        float* __restrict__ ws, float* __restrict__ out) {
    if (blockIdx.x == 0 && threadIdx.x == 0) *out = 0.0f;  // init for reduce's atomicAdd

    const bool p1 = (int)blockIdx.x < NBLK1;
    const float2* rowsS; const float2* colsS; float* P;
    float rowD, colD; int rowMax, colMax, nrows, ncols, g, s, pstr;
    if (p1) {
        int f = (int)blockIdx.x;
        g = f % G1; s = f / G1;
        rowsS = srcA; rowD = DELTA_A; rowMax = SRC_A - 1; nrows = NA;
        colsS = srcB; colD = DELTA_B; colMax = SRC_B - 1; ncols = NB;
        P = ws; pstr = PSTR1;
    } else {
        int f = (int)blockIdx.x - NBLK1;
        g = f % G2; s = f / G2;
        rowsS = srcB; rowD = DELTA_B; rowMax = SRC_B - 1; nrows = NB;
        colsS = srcA; colD = DELTA_A; colMax = SRC_A - 1; ncols = NA;
        P = ws + PART2_OFF; pstr = PSTR2;
    }

    // stage this block's column slice in LDS as (2qx, 2qy, -|q|^2, 0)
    __shared__ __align__(16) float4 sc[SLICE];
    int c0 = s * SLICE;
    int cw = ncols - c0; if (cw > SLICE) cw = SLICE;
    if ((int)threadIdx.x < cw) {
        int cidx = (int)((float)(c0 + (int)threadIdx.x) * colD);
        if (cidx > colMax) cidx = colMax;
        float2 q = colsS[cidx];
        float n2 = fmaf(q.x, q.x, q.y * q.y);
        sc[threadIdx.x] = make_float4(q.x + q.x, q.y + q.y, -n2, 0.0f);
    }
    __syncthreads();

    // rows: inline linspace gather (clamp load, guard store)
    float px[RPT], py[RPT], pp[RPT], M[RPT];
    int r0 = g * RPB + (int)threadIdx.x;
#pragma unroll
    for (int i = 0; i < RPT; ++i) {
        int r = r0 + i * BLOCK;
        int l = r < nrows ? r : nrows - 1;
        int ridx = (int)((float)l * rowD);
        if (ridx > rowMax) ridx = rowMax;
        float2 q = rowsS[ridx];
        px[i] = q.x; py[i] = q.y;
        pp[i] = fmaf(q.x, q.x, q.y * q.y);
        M[i] = -__builtin_inff();
    }

    if (cw == SLICE) {
        // hot path (113 of 115 slices): compile-time trip count
#pragma unroll 4
        for (int k = 0; k < SLICE; ++k) {
            float4 q = sc[k];  // broadcast across the wave: conflict-free
#pragma unroll
            for (int i = 0; i < RPT; ++i)
                M[i] = fmaxf(M[i], fmaf(px[i], q.x, fmaf(py[i], q.y, q.z)));
        }
    } else {
        for (int k = 0; k < cw; ++k) {
            float4 q = sc[k];
#pragma unroll
            for (int i = 0; i < RPT; ++i)
                M[i] = fmaxf(M[i], fmaf(px[i], q.x, fmaf(py[i], q.y, q.z)));
        }
    }

    // plain coalesced stores of partial min d^2 (no atomics)
#pragma unroll
    for (int i = 0; i < RPT; ++i) {
        int r = r0 + i * BLOCK;
        if (r < nrows) P[s * pstr + r] = pp[i] - M[i];
    }
}

// ---- reduce: 64 rows/block x 4 chunk-slices, coalesced, then LDS+shuffle ----
#define RB_ROWS 64
#define RB1 125   // 8000/64 (exact)
#define RB2 157   // ceil(10000/64)

__global__ __launch_bounds__(BLOCK) void reduce_out(const float* __restrict__ ws,
                                                    float* __restrict__ out) {
    int t  = (int)threadIdx.x;
    int rl = t & 63;        // row within block
    int sl = t >> 6;        // chunk-slice 0..3
    const bool p1 = (int)blockIdx.x < RB1;
    const float* P; int nrows, nch, pstr, rbase; float scale;
    if (p1) {
        P = ws;             nrows = NA; nch = S1; pstr = PSTR1;
        rbase = (int)blockIdx.x * RB_ROWS;         scale = 0.5f / (float)NA;
    } else {
        P = ws + PART2_OFF; nrows = NB; nch = S2; pstr = PSTR2;
        rbase = ((int)blockIdx.x - RB1) * RB_ROWS; scale = 0.5f / (float)NB;
    }
    int r = rbase + rl;                 // < pstr (padded); value guarded at use
    int per = (nch + 3) >> 2;
    int cb = sl * per;
    int ce = cb + per; if (ce > nch) ce = nch;

    float mn = __builtin_inff();
#pragma unroll 8
    for (int c = cb; c < ce; ++c) mn = fminf(mn, P[c * pstr + r]);

    __shared__ float red[4][RB_ROWS];
    red[sl][rl] = mn;
    __syncthreads();

    if (t < 64) {
        float m = fminf(fminf(red[0][rl], red[1][rl]),
                        fminf(red[2][rl], red[3][rl]));
        m = fmaxf(m, 0.0f);  // expanded form can round slightly negative
        float v = (r < nrows) ? sqrtf(m) * scale : 0.0f;
        for (int off = 32; off > 0; off >>= 1) v += __shfl_down(v, off, 64);
        if (rl == 0) atomicAdd(out, v);
    }
}

extern "C" void kernel_launch(void* const* d_in, const int* in_sizes, int n_in,
                              void* d_out, int out_size, void* d_ws, size_t ws_size,
                              hipStream_t stream) {
    (void)in_sizes; (void)n_in; (void)out_size; (void)ws_size;
    const float2* srcA = (const float2*)d_in[0];  // img_render_points (1000*64*2)
    const float2* srcB = (const float2*)d_in[1];  // ref point cloud (80000*2)
    float* ws = (float*)d_ws;
    float* out = (float*)d_out;

    chamfer_partial<<<NBLK1 + NBLK2, BLOCK, 0, stream>>>(srcA, srcB, ws, out);
    reduce_out<<<RB1 + RB2, BLOCK, 0, stream>>>(ws, out);
}